// Round 3
// baseline (7354.855 us; speedup 1.0000x reference)
//
#include <hip/hip_runtime.h>
#include <stdint.h>

#define TLEN 1024
#define BATCH 64
#define DIMX 128
#define HID 512
#define ROWSTR 520           // ushorts per LDS h row (1040 B: +8 pad -> balanced banks)

typedef __attribute__((ext_vector_type(8))) short short8;
typedef __attribute__((ext_vector_type(4))) float f32x4;

// ---- workspace layout (bytes) ----
#define OFF_WT   0u           // Wt: [2048][640] bf16 = 2,621,440
#define OFF_XBF  2621440u     // xbf: [64][1024][128] bf16 = 16,777,216
#define OFF_HB   19398656u    // hb: [2][64][512] u32 (tagged bf16) = 262,144
#define OFF_ACC  19660800u    // acc: 64

__device__ __forceinline__ unsigned short f2bf(float f) {
  unsigned u = __float_as_uint(f);
  u += 0x7fffu + ((u >> 16) & 1u);
  return (unsigned short)(u >> 16);
}
__device__ __forceinline__ float sigm(float x) { return 1.0f / (1.0f + __expf(-x)); }
__device__ __forceinline__ float tanh_fast(float x) {
  float a = fabsf(x);
  float e = __expf(2.0f * a);
  float t = 1.0f - 2.0f / (e + 1.0f);
  return copysignf(t, x);
}
__device__ __forceinline__ unsigned long long aload64(const unsigned* p) {
  return __hip_atomic_load((const unsigned long long*)p, __ATOMIC_RELAXED,
                           __HIP_MEMORY_SCOPE_AGENT);
}

// ---- x fp32 -> bf16, coalesced ----
__global__ void k_convx(const float4* __restrict__ x4, ushort4* __restrict__ o4) {
  int i = blockIdx.x * 256 + threadIdx.x;
  float4 v = x4[i];
  ushort4 o;
  o.x = f2bf(v.x); o.y = f2bf(v.y); o.z = f2bf(v.z); o.w = f2bf(v.w);
  o4[i] = o;
}

// ---- build Wt[col 0..2047][k 0..639] bf16 = concat(Wx;Wh)^T (proven) ----
__global__ void k_tw(const float* __restrict__ Wx, const float* __restrict__ Wh,
                     unsigned short* __restrict__ Wt) {
  __shared__ float tile[32][65];
  int bk = blockIdx.x;
  int k0 = (bk / 64) * 64;
  int c0 = (bk % 64) * 32;
  int tid = threadIdx.x;
  const float* src = (k0 < 128) ? (Wx + (size_t)k0 * 2048)
                                : (Wh + (size_t)(k0 - 128) * 2048);
#pragma unroll
  for (int p = 0; p < 8; ++p) {
    int i = p * 256 + tid;
    int kk = i >> 5, cc = i & 31;
    tile[cc][kk] = src[(size_t)kk * 2048 + (c0 + cc)];
  }
  __syncthreads();
  int cc = tid >> 3, ch = tid & 7;
  unsigned short tmp[8];
#pragma unroll
  for (int j = 0; j < 8; ++j) tmp[j] = f2bf(tile[cc][ch * 8 + j]);
  uint4 o;
  o.x = (unsigned)tmp[0] | ((unsigned)tmp[1] << 16);
  o.y = (unsigned)tmp[2] | ((unsigned)tmp[3] << 16);
  o.z = (unsigned)tmp[4] | ((unsigned)tmp[5] << 16);
  o.w = (unsigned)tmp[6] | ((unsigned)tmp[7] << 16);
  *(uint4*)(Wt + (size_t)(c0 + cc) * 640 + k0 + ch * 8) = o;
}

// ---- recurrence: 128 WGs = 8 groups x 16 WGs(512thr = 8 waves) ----
// Wave layout: full K=640, 16 N-cols = 4 gates x 4 h-cols interleaved (gate=n&3).
// Each wave also services batch-row w: polls tagged h from LLC once per WG,
// broadcasts via double-buffered LDS. One __syncthreads per step.
__global__ __launch_bounds__(512, 1) void k_lstm(
    const unsigned short* __restrict__ xbf,   // [B][T][D] bf16
    const unsigned short* __restrict__ Wt,    // [4H][640] bf16 (B^T layout)
    const float* __restrict__ bias,           // [4H]
    const float* __restrict__ Wo,             // [H][2]
    unsigned* __restrict__ hb,                // [2][B][H] tagged u32
    float* __restrict__ out)                  // [B][T][2] logits via atomicAdd
{
  __shared__ unsigned short hlds[2][8][ROWSTR];   // 2 x 8 rows x 520 (8320 B/buf)

  const int tid  = threadIdx.x;
  const int w    = tid >> 6;      // wave 0..7 (also: polled batch row)
  const int lane = tid & 63;
  const int q    = lane >> 4;
  const int n    = lane & 15;
  const int grp  = blockIdx.x & 7;
  const int hw   = blockIdx.x >> 3;   // 0..15
  const int g0   = grp * 8;

  // zero LDS buf0 (h_0 = 0)
  for (int i = tid; i < (8 * ROWSTR) / 2; i += 512)
    ((unsigned*)&hlds[0][0][0])[i] = 0u;

  const int gate = n & 3;
  const int hc   = hw * 32 + w * 4 + (n >> 2);
  const int gcol = gate * HID + hc;
  const int arow = (n < 8) ? n : 7;     // A-frag row clamp (rows 8..15 unused)

  // ---- pin full-K weight column in registers: 20 frags = 80 VGPRs ----
  short8 Bf[20];
#pragma unroll
  for (int kk = 0; kk < 20; ++kk)
    Bf[kk] = *(const short8*)(Wt + (size_t)gcol * 640 + kk * 32 + q * 8);

  const float bv = bias[gcol];
  const float2 wo = ((const float2*)Wo)[hc];
  float cst[4] = {0.f, 0.f, 0.f, 0.f};

  const unsigned short* xrow = xbf + (size_t)(g0 + arow) * (TLEN * DIMX) + q * 8;
  short8 ax[4];
#pragma unroll
  for (int kk = 0; kk < 4; ++kk)
    ax[kk] = *(const short8*)(xrow + kk * 32);   // t = 0

  const char* ldsrd = (const char*)&hlds[0][0][0] + arow * (ROWSTR * 2) + q * 16;
  char* ldswr = (char*)&hlds[0][0][0] + w * (ROWSTR * 2) + lane * 16;
  const unsigned* pollbase = hb + (size_t)(g0 + w) * HID + lane * 8;
  const int sb = lane & 0x3C;   // quad base for gate gather

#pragma unroll 1
  for (int t = 0; t < TLEN; ++t) {
    __syncthreads();

    // ---- MFMA: z = [x_t, h_t] @ W (full K per wave), 4 acc chains ----
    f32x4 ac0 = {bv, bv, bv, bv}, ac1 = {0,0,0,0}, ac2 = {0,0,0,0}, ac3 = {0,0,0,0};
    ac0 = __builtin_amdgcn_mfma_f32_16x16x32_bf16(ax[0], Bf[0], ac0, 0, 0, 0);
    ac1 = __builtin_amdgcn_mfma_f32_16x16x32_bf16(ax[1], Bf[1], ac1, 0, 0, 0);
    ac2 = __builtin_amdgcn_mfma_f32_16x16x32_bf16(ax[2], Bf[2], ac2, 0, 0, 0);
    ac3 = __builtin_amdgcn_mfma_f32_16x16x32_bf16(ax[3], Bf[3], ac3, 0, 0, 0);
    {
      const char* hp = ldsrd + (t & 1) * 8320;
#pragma unroll
      for (int kk = 4; kk < 20; kk += 4) {
        short8 a0 = *(const short8*)(hp + (kk - 4) * 64);
        short8 a1 = *(const short8*)(hp + (kk - 3) * 64);
        short8 a2 = *(const short8*)(hp + (kk - 2) * 64);
        short8 a3 = *(const short8*)(hp + (kk - 1) * 64);
        ac0 = __builtin_amdgcn_mfma_f32_16x16x32_bf16(a0, Bf[kk + 0], ac0, 0, 0, 0);
        ac1 = __builtin_amdgcn_mfma_f32_16x16x32_bf16(a1, Bf[kk + 1], ac1, 0, 0, 0);
        ac2 = __builtin_amdgcn_mfma_f32_16x16x32_bf16(a2, Bf[kk + 2], ac2, 0, 0, 0);
        ac3 = __builtin_amdgcn_mfma_f32_16x16x32_bf16(a3, Bf[kk + 3], ac3, 0, 0, 0);
      }
    }
    f32x4 z = (ac0 + ac1) + (ac2 + ac3);

    // ---- gather 4 gates of my h-col from quad lanes ----
    float zi[4], zf[4], zg[4], zo[4];
#pragma unroll
    for (int r = 0; r < 4; ++r) {
      zi[r] = __shfl(z[r], sb | 0);
      zf[r] = __shfl(z[r], sb | 1);
      zg[r] = __shfl(z[r], sb | 2);
      zo[r] = __shfl(z[r], sb | 3);
    }
    float hv[4];
#pragma unroll
    for (int r = 0; r < 4; ++r) {
      float ig = sigm(zi[r]), fg = sigm(zf[r]);
      float gg = tanh_fast(zg[r]), og = sigm(zo[r]);
      cst[r] = fg * cst[r] + ig * gg;
      hv[r] = og * tanh_fast(cst[r]);
    }

    // ---- store tagged h (one lane per col) ----
    if (gate == 0 && q < 2) {
      unsigned* dst = hb + (size_t)((t + 1) & 1) * (BATCH * HID) +
                      (size_t)(g0 + q * 4) * HID + hc;
      unsigned tg = (unsigned)((t + 1) & 0xFFFF);
#pragma unroll
      for (int r = 0; r < 4; ++r)
        __hip_atomic_store(dst + (size_t)r * HID,
                           ((unsigned)f2bf(hv[r]) << 16) | tg,
                           __ATOMIC_RELAXED, __HIP_MEMORY_SCOPE_AGENT);
    }

    // ---- prefetch next step's x fragments (off critical path) ----
    {
      int tn = (t + 1 < TLEN) ? t + 1 : t;
      const unsigned short* xp = xrow + (size_t)tn * DIMX;
#pragma unroll
      for (int kk = 0; kk < 4; ++kk)
        ax[kk] = *(const short8*)(xp + kk * 32);
    }

    // ---- logit partials -> atomicAdd ----
#pragma unroll
    for (int r = 0; r < 4; ++r) {
      float m0 = (gate == 0) ? hv[r] * wo.x : 0.f;
      float m1 = (gate == 0) ? hv[r] * wo.y : 0.f;
      m0 += __shfl_xor(m0, 4); m1 += __shfl_xor(m1, 4);
      m0 += __shfl_xor(m0, 8); m1 += __shfl_xor(m1, 8);
      if (n == 0 && q < 2) {
        float* po = out + ((size_t)(g0 + q * 4 + r) * TLEN + t) * 2;
        atomicAdd(po + 0, m0);
        atomicAdd(po + 1, m1);
      }
    }

    // ---- service duty: poll my batch row (g0+w) for tag t+1, stage to LDS ----
    if (t + 1 < TLEN) {
      const unsigned* src = pollbase + (size_t)((t + 1) & 1) * (BATCH * HID);
      unsigned long long rep = (unsigned)((t + 1) & 0xFFFF);
      rep |= rep << 32;
      const unsigned long long MSK = 0x0000FFFF0000FFFFull;
      unsigned long long wb0, wb1, wb2, wb3;
      int guard = 0;
      for (;;) {
        wb0 = aload64(src + 0);
        wb1 = aload64(src + 2);
        wb2 = aload64(src + 4);
        wb3 = aload64(src + 6);
        unsigned long long d = (wb0 ^ rep) | (wb1 ^ rep) | (wb2 ^ rep) | (wb3 ^ rep);
        bool bad = (d & MSK) != 0ull;
        if (__ballot(bad) == 0ull || ++guard > (1 << 20)) break;
      }
      uint4 pk;
      pk.x = ((unsigned)wb0 >> 16) | ((unsigned)(wb0 >> 32) & 0xFFFF0000u);
      pk.y = ((unsigned)wb1 >> 16) | ((unsigned)(wb1 >> 32) & 0xFFFF0000u);
      pk.z = ((unsigned)wb2 >> 16) | ((unsigned)(wb2 >> 32) & 0xFFFF0000u);
      pk.w = ((unsigned)wb3 >> 16) | ((unsigned)(wb3 >> 32) & 0xFFFF0000u);
      *(uint4*)(ldswr + ((t + 1) & 1) * 8320) = pk;
    }
  }
}

// ---- logits -> softmax probs + NLL ----
__global__ void k_out2(float* __restrict__ out, const float* __restrict__ bo,
                       const int* __restrict__ labels, float* __restrict__ acc) {
  __shared__ float sred[4];
  int i = blockIdx.x * 256 + threadIdx.x;   // 0..65535 = b*T + t
  float l0 = out[(size_t)i * 2 + 0] + bo[0];
  float l1 = out[(size_t)i * 2 + 1] + bo[1];
  float mx = fmaxf(l0, l1);
  float e0 = __expf(l0 - mx), e1 = __expf(l1 - mx);
  float s = e0 + e1, inv = 1.0f / s;
  out[(size_t)i * 2 + 0] = e0 * inv;
  out[(size_t)i * 2 + 1] = e1 * inv;
  int lab = labels[i];
  float nll = __logf(s) - ((lab ? l1 : l0) - mx);
#pragma unroll
  for (int off = 32; off >= 1; off >>= 1) nll += __shfl_xor(nll, off);
  if ((threadIdx.x & 63) == 0) sred[threadIdx.x >> 6] = nll;
  __syncthreads();
  if (threadIdx.x == 0)
    atomicAdd(acc, sred[0] + sred[1] + sred[2] + sred[3]);
}

__global__ void k_fin(const float* __restrict__ acc, float* __restrict__ out) {
  out[BATCH * TLEN * 2] = acc[0] * (1.0f / (float)(BATCH * TLEN));
}

extern "C" void kernel_launch(void* const* d_in, const int* in_sizes, int n_in,
                              void* d_out, int out_size, void* d_ws, size_t ws_size,
                              hipStream_t stream) {
  const float* x      = (const float*)d_in[0];
  const int*   labels = (const int*)d_in[1];
  const float* Wx     = (const float*)d_in[2];
  const float* Wh     = (const float*)d_in[3];
  const float* b      = (const float*)d_in[4];
  const float* Wo     = (const float*)d_in[5];
  const float* bo     = (const float*)d_in[6];
  float* out = (float*)d_out;
  char* ws = (char*)d_ws;

  unsigned short* Wt  = (unsigned short*)(ws + OFF_WT);
  unsigned short* xbf = (unsigned short*)(ws + OFF_XBF);
  unsigned*       hb  = (unsigned*)(ws + OFF_HB);
  float*          acc = (float*)(ws + OFF_ACC);

  // hb zero => h_0 = 0 with tag 0; acc zero; out zero (atomic target)
  hipMemsetAsync(ws + OFF_HB, 0, 262144 + 64, stream);
  hipMemsetAsync(d_out, 0, (size_t)BATCH * TLEN * 2 * sizeof(float), stream);
  k_convx<<<8192, 256, 0, stream>>>((const float4*)x, (ushort4*)xbf);
  k_tw<<<640, 256, 0, stream>>>(Wx, Wh, Wt);
  k_lstm<<<128, 512, 0, stream>>>(xbf, Wt, b, Wo, hb, out);
  k_out2<<<256, 256, 0, stream>>>(out, bo, labels, acc);
  k_fin<<<1, 1, 0, stream>>>(acc, out);
}